// Round 1
// baseline (79.665 us; speedup 1.0000x reference)
//
#include <hip/hip_runtime.h>

#define TWO_PI_F 6.283185307179586f
#define L2T_OVER_64 0.20762050594f  /* log2(10000)/64 */

// Kernel 1: per-batch exclusive offset (sum of num_nodes[0..b-1]) and
// per-batch max of centroid x/y over valid nodes -> store 2pi/(max+eps).
__global__ void prep_kernel(const float* __restrict__ centroid,
                            const int* __restrict__ num_nodes,
                            int B, int N,
                            int* __restrict__ offsets,
                            float* __restrict__ inv_x,
                            float* __restrict__ inv_y) {
    __shared__ int s_i[256];
    __shared__ float s_x[256];
    __shared__ float s_y[256];
    const int b = blockIdx.x;
    const int t = threadIdx.x;

    int nn_t = (t < B) ? num_nodes[t] : 0;
    s_i[t] = (t < b) ? nn_t : 0;
    __syncthreads();
    for (int s = 128; s > 0; s >>= 1) {
        if (t < s) s_i[t] += s_i[t + s];
        __syncthreads();
    }
    const int offset = s_i[0];
    __syncthreads();

    const int nn = num_nodes[b];
    const int n_eff = (nn < N) ? nn : N;
    float mx = 0.0f, my = 0.0f;   // padded zeros participate in the max (coords >= 0)
    for (int j = t; j < n_eff; j += 256) {
        float2 c = ((const float2*)centroid)[offset + j];
        mx = fmaxf(mx, c.x);
        my = fmaxf(my, c.y);
    }
    s_x[t] = mx; s_y[t] = my;
    __syncthreads();
    for (int s = 128; s > 0; s >>= 1) {
        if (t < s) {
            s_x[t] = fmaxf(s_x[t], s_x[t + s]);
            s_y[t] = fmaxf(s_y[t], s_y[t + s]);
        }
        __syncthreads();
    }
    if (t == 0) {
        offsets[b] = offset;
        inv_x[b] = TWO_PI_F / (s_x[0] + 1e-6f);
        inv_y[b] = TWO_PI_F / (s_y[0] + 1e-6f);
    }
}

// Kernel 2: one 64-lane group per output row (b, j); 4 rows per 256-thread block.
// Each lane: one float4 of features, one float4 of pos_emd, lane0 writes mask.
__global__ void main_kernel(const float* __restrict__ patch,
                            const float* __restrict__ centroid,
                            const int* __restrict__ num_nodes,
                            const int* __restrict__ offsets,
                            const float* __restrict__ inv_x,
                            const float* __restrict__ inv_y,
                            int N, int rows,
                            float* __restrict__ out_feat,
                            float* __restrict__ out_mask,
                            float* __restrict__ out_emb) {
    const int tid = threadIdx.x;
    const int r = tid >> 6;
    const int lane = tid & 63;
    const int row = blockIdx.x * 4 + r;
    if (row >= rows) return;
    const int b = row / N;
    const int j = row - b * N;

    const int nn = num_nodes[b];
    const int n_eff = (nn < N) ? nn : N;
    const bool valid = (j < n_eff);

    float4 f = make_float4(0.f, 0.f, 0.f, 0.f);
    float x = 0.f, y = 0.f;
    if (valid) {
        const int src = offsets[b] + j;
        f = ((const float4*)(patch + (size_t)src * 256))[lane];
        float2 c = ((const float2*)centroid)[src];
        x = c.x; y = c.y;
    }
    ((float4*)(out_feat + (size_t)row * 256))[lane] = f;

    if (lane == 0)
        out_mask[row] = (j >= nn + 1) ? 1.0f : 0.0f;

    // pos_emd row: elements [0,128) from y, [128,256) from x.
    // element e: i = e & 127, pair k = i >> 1, inv = 10000^(-k/64),
    // out = (i odd) ? cos(a*inv) : sin(a*inv)  (same arg within a pair).
    const float a = (lane < 32) ? (y * inv_y[b]) : (x * inv_x[b]);
    const int m = lane & 31;             // covers elements 4m..4m+3 of this half
    const float inv0 = exp2f(-(float)(2 * m)     * L2T_OVER_64);
    const float inv1 = exp2f(-(float)(2 * m + 1) * L2T_OVER_64);
    float s0, c0, s1, c1;
    __sincosf(a * inv0, &s0, &c0);
    __sincosf(a * inv1, &s1, &c1);
    ((float4*)(out_emb + (size_t)row * 256))[lane] = make_float4(s0, c0, s1, c1);
}

extern "C" void kernel_launch(void* const* d_in, const int* in_sizes, int n_in,
                              void* d_out, int out_size, void* d_ws, size_t ws_size,
                              hipStream_t stream) {
    (void)n_in; (void)ws_size;
    const float* patch     = (const float*)d_in[0];
    const float* centroid  = (const float*)d_in[1];
    const int*   num_nodes = (const int*)d_in[2];

    const int B = in_sizes[2];                 // 256
    const int C = 256;                         // patch feature dim (fixed by problem)
    const int N = out_size / (B * (C + 257));  // features(C) + mask(1) + emb(256) per row -> 512

    float* out_feat = (float*)d_out;
    float* out_mask = out_feat + (size_t)B * N * C;
    float* out_emb  = out_mask + (size_t)B * N;

    int*   offsets = (int*)d_ws;
    float* inv_x   = (float*)d_ws + B;
    float* inv_y   = inv_x + B;

    prep_kernel<<<B, 256, 0, stream>>>(centroid, num_nodes, B, N, offsets, inv_x, inv_y);

    const int rows = B * N;
    main_kernel<<<(rows + 3) / 4, 256, 0, stream>>>(
        patch, centroid, num_nodes, offsets, inv_x, inv_y,
        N, rows, out_feat, out_mask, out_emb);
}